// Round 11
// baseline (55.478 us; speedup 1.0000x reference)
//
#include <hip/hip_runtime.h>
#include <math.h>

#define NPTS 8192

typedef _Float16 half8  __attribute__((ext_vector_type(8)));
typedef float    f32x16 __attribute__((ext_vector_type(16)));

__device__ __forceinline__ float min3a(float m, float a, float b) {
    float r;
    asm("v_min3_f32 %0, %1, %2, %3" : "=v"(r) : "v"(m), "v"(a), "v"(b));
    return r;
}

// ---------------------------------------------------------------------------
// dist(q,p) = qn + pn - 2 q.p via TWO C-CHAINED 32x32x16_f16 MFMAs that use
// ONLY the h==0 (k0-7) slots — the slot-pairing R9 verified end-to-end.
// h==1 halves of ALL fragments are zero (R7/R10 failures localize to the
// unverified h==1 A<->B pairing).  Balanced power-of-2 scaling keeps every
// f16 operand normal (no flush):
//   MFMA1: A {ahx,ahy,ahz,qnh,one,al64x,al64y,al64z}
//          B {phx,phy,phz,one,pnh,ph64x,ph64y,ph64z}   -> a.ph + qn_h + pn_h
//   MFMA2: A {ah64x,ah64y,ah64z,qnl64,i64,0,0,0}
//          B {pl64x,pl64y,pl64z,i64,pnl64,0,0,0}, C=D1 -> + ah.pl + qnl + pnl
// (a=-2q; vh=f16(v); vl64=f16((v-vh)*64); vh64=f16(vh/64); dropped al.pl
//  ~1e-5.)  Full dist lands in the accumulator -> min3 only, no combine.
// C/D layout (m74/m101): col=lane&31, row=(reg&3)+8*(reg>>2)+4*(lane>>5);
// threshold+sum is permutation-invariant anyway.
// ---------------------------------------------------------------------------

// Prep: thread per (combo, tile, lane); writes the (B1,B2) fragment pair.
// h==1 lanes store ZERO fragments so the main loop loads branchlessly.
__global__ __launch_bounds__(256) void prep_bfrag(
    const float* __restrict__ xyz1,
    const float* __restrict__ xyz2,
    half8* __restrict__ bfrag)
{
    const int gid  = blockIdx.x * 256 + threadIdx.x;
    const int lane = gid & 63;
    const int tile = (gid >> 6) & 255;
    const int c    = gid >> 14;            // set*4 + b
    const int s    = c >> 2, bb = c & 3;
    const int col  = lane & 31, h = lane >> 5;

    half8 B1 = {}, B2 = {};
    if (h == 0) {
        const float* src = (s == 0 ? xyz1 : xyz2)
                         + ((size_t)bb * NPTS + tile * 32 + col) * 3;
        const float px = src[0], py = src[1], pz = src[2];
        const _Float16 phx = (_Float16)px, phy = (_Float16)py, phz = (_Float16)pz;
        const _Float16 pl64x = (_Float16)((px - (float)phx) * 64.0f);
        const _Float16 pl64y = (_Float16)((py - (float)phy) * 64.0f);
        const _Float16 pl64z = (_Float16)((pz - (float)phz) * 64.0f);
        const _Float16 ph64x = (_Float16)((float)phx * (1.0f / 64.0f));
        const _Float16 ph64y = (_Float16)((float)phy * (1.0f / 64.0f));
        const _Float16 ph64z = (_Float16)((float)phz * (1.0f / 64.0f));
        const float pn = px * px + py * py + pz * pz;
        const _Float16 pnh = (_Float16)pn;
        const _Float16 pnl64 = (_Float16)((pn - (float)pnh) * 64.0f);
        const _Float16 one = (_Float16)1.0f, i64 = (_Float16)(1.0f / 64.0f);
        const _Float16 z = (_Float16)0.0f;
        B1 = (half8){phx, phy, phz, one, pnh, ph64x, ph64y, ph64z};
        B2 = (half8){pl64x, pl64y, pl64z, i64, pnl64, z, z, z};
    }
    half8* dst = bfrag + ((size_t)(c * 256 + tile) * 2) * 64 + lane;
    dst[0]  = B1;
    dst[64] = B2;
}

// Main: 512 blocks = (dir, b, qchunk of 128 queries). 8 waves = 8 disjoint
// point-eighths (32 tiles each, no duplicate reads). Per wave: 4 q-tile A
// fragment pairs in regs + m[4] f32x16 running mins; point tiles streamed
// in pairs (branchless &31-wrapped prefetch) from ws (L2-hot).
// Per tile-pair per q-tile: 4 chained mfma + 16 v_min3.
__global__ __launch_bounds__(512, 2) void chamfer_mfma(
    const float* __restrict__ xyz1,
    const float* __restrict__ xyz2,
    const half8* __restrict__ bfrag,
    const float* __restrict__ thp,
    double* __restrict__ partial)
{
    __shared__ float  red[8][4][32];
    __shared__ double wsum[8];

    const int bid    = blockIdx.x;
    const int qchunk = bid & 63;            // 128-query chunk
    const int combo  = bid >> 6;            // dir*4 + b
    const int b      = combo & 3;
    const int dir    = combo >> 2;
    const float* Q   = (dir == 0 ? xyz1 : xyz2) + (size_t)b * NPTS * 3;
    const int   cref = (dir == 0 ? 4 : 0) + b;

    const int lane = threadIdx.x & 63;
    const int w    = threadIdx.x >> 6;      // point-eighth
    const int h    = lane >> 5;
    const int col  = lane & 31;

    half8 A1[4], A2[4];
    f32x16 m[4];
    #pragma unroll
    for (int lt = 0; lt < 4; ++lt) {
        A1[lt] = (half8){};
        A2[lt] = (half8){};
        if (h == 0) {
            const float* qp = Q + ((size_t)qchunk * 128 + lt * 32 + col) * 3;
            const float qx = qp[0], qy = qp[1], qz = qp[2];
            const float ax = -2.0f * qx, ay = -2.0f * qy, az = -2.0f * qz;
            const _Float16 ahx = (_Float16)ax, ahy = (_Float16)ay, ahz = (_Float16)az;
            const _Float16 al64x = (_Float16)((ax - (float)ahx) * 64.0f);
            const _Float16 al64y = (_Float16)((ay - (float)ahy) * 64.0f);
            const _Float16 al64z = (_Float16)((az - (float)ahz) * 64.0f);
            const _Float16 ah64x = (_Float16)((float)ahx * (1.0f / 64.0f));
            const _Float16 ah64y = (_Float16)((float)ahy * (1.0f / 64.0f));
            const _Float16 ah64z = (_Float16)((float)ahz * (1.0f / 64.0f));
            const float qn = qx * qx + qy * qy + qz * qz;
            const _Float16 qnh = (_Float16)qn;
            const _Float16 qnl64 = (_Float16)((qn - (float)qnh) * 64.0f);
            const _Float16 one = (_Float16)1.0f, i64 = (_Float16)(1.0f / 64.0f);
            const _Float16 z16 = (_Float16)0.0f;
            A1[lt] = (half8){ahx, ahy, ahz, qnh, one, al64x, al64y, al64z};
            A2[lt] = (half8){ah64x, ah64y, ah64z, qnl64, i64, z16, z16, z16};
        }
        #pragma unroll
        for (int i = 0; i < 16; ++i) m[lt][i] = INFINITY;
    }

    f32x16 zc;
    #pragma unroll
    for (int i = 0; i < 16; ++i) zc[i] = 0.0f;

    const half8* bf = bfrag + (size_t)cref * (256 * 2 * 64) + lane;
    const int t0 = w * 32;

#define LD(t, f) bf[(size_t)(((t0 + ((t) & 31)) * 2 + (f))) * 64]

    half8 h0 = LD(0, 0), l0 = LD(0, 1);
    half8 h1 = LD(1, 0), l1 = LD(1, 1);
    #pragma unroll 1
    for (int jp = 0; jp < 16; ++jp) {
        half8 nh0 = LD(2 * jp + 2, 0), nl0 = LD(2 * jp + 2, 1);
        half8 nh1 = LD(2 * jp + 3, 0), nl1 = LD(2 * jp + 3, 1);
        #pragma unroll
        for (int lt = 0; lt < 4; ++lt) {
            f32x16 D = __builtin_amdgcn_mfma_f32_32x32x16_f16(A1[lt], h0, zc, 0, 0, 0);
            D = __builtin_amdgcn_mfma_f32_32x32x16_f16(A2[lt], l0, D, 0, 0, 0);
            f32x16 E = __builtin_amdgcn_mfma_f32_32x32x16_f16(A1[lt], h1, zc, 0, 0, 0);
            E = __builtin_amdgcn_mfma_f32_32x32x16_f16(A2[lt], l1, E, 0, 0, 0);
            #pragma unroll
            for (int i = 0; i < 16; ++i)
                m[lt][i] = min3a(m[lt][i], D[i], E[i]);
        }
        h0 = nh0; l0 = nl0; h1 = nh1; l1 = nl1;
    }
#undef LD

    // Min over the 32 point-columns within each 32-lane half.
    #pragma unroll
    for (int lt = 0; lt < 4; ++lt) {
        #pragma unroll
        for (int i = 0; i < 16; ++i) {
            float v = m[lt][i];
            v = fminf(v, __shfl_xor(v, 1, 64));
            v = fminf(v, __shfl_xor(v, 2, 64));
            v = fminf(v, __shfl_xor(v, 4, 64));
            v = fminf(v, __shfl_xor(v, 8, 64));
            v = fminf(v, __shfl_xor(v, 16, 64));
            m[lt][i] = v;
        }
    }
    if (col == 0) {
        #pragma unroll
        for (int lt = 0; lt < 4; ++lt)
            #pragma unroll
            for (int i = 0; i < 16; ++i)
                red[w][lt][(i & 3) + 8 * (i >> 2) + 4 * h] = m[lt][i];
    }
    __syncthreads();

    // Combine the 8 point-eighth waves per query row; threshold; sum.
    double val = 0.0;
    if (threadIdx.x < 128) {
        const int lt = threadIdx.x >> 5;
        const int r  = threadIdx.x & 31;
        float mv = red[0][lt][r];
        #pragma unroll
        for (int ww = 1; ww < 8; ++ww) mv = fminf(mv, red[ww][lt][r]);
        val = (mv <= *thp) ? 0.0 : (double)mv;
    }
    for (int off = 32; off > 0; off >>= 1)
        val += __shfl_down(val, off, 64);
    if (lane == 0) wsum[w] = val;
    __syncthreads();
    if (threadIdx.x == 0) {
        double s = 0.0;
        #pragma unroll
        for (int i = 0; i < 8; ++i) s += wsum[i];
        partial[bid] = s;
    }
}

// out[b] = (sum of the 128 partials of batch b) / 8192  (mean d1 + mean d2).
__global__ __launch_bounds__(256) void chamfer_fin(
    const double* __restrict__ partial,
    float* __restrict__ out)
{
    const int b = threadIdx.x >> 6;         // wave id = batch
    const int l = threadIdx.x & 63;
    double v = partial[b * 64 + l] + partial[(4 + b) * 64 + l];
    for (int off = 32; off > 0; off >>= 1)
        v += __shfl_down(v, off, 64);
    if (l == 0) out[b] = (float)(v / (double)NPTS);
}

extern "C" void kernel_launch(void* const* d_in, const int* in_sizes, int n_in,
                              void* d_out, int out_size, void* d_ws, size_t ws_size,
                              hipStream_t stream) {
    const float* xyz1 = (const float*)d_in[0];
    const float* xyz2 = (const float*)d_in[1];
    const float* thp  = (const float*)d_in[2];
    float* out        = (float*)d_out;

    half8*  bfrag   = (half8*)d_ws;         // 8*256*2*64*16 B = 4 MiB
    double* partial = (double*)((char*)d_ws + (size_t)8 * 256 * 2 * 64 * 16);

    prep_bfrag<<<512, 256, 0, stream>>>(xyz1, xyz2, bfrag);
    chamfer_mfma<<<512, 512, 0, stream>>>(xyz1, xyz2, bfrag, thp, partial);
    chamfer_fin<<<1, 256, 0, stream>>>(partial, out);
}